// Round 5
// baseline (404.544 us; speedup 1.0000x reference)
//
#include <hip/hip_runtime.h>
#include <hip/hip_bf16.h>

typedef short s16x8 __attribute__((ext_vector_type(8)));
typedef float f32x4 __attribute__((ext_vector_type(4)));

#define B_ 16
#define L_ 2048
#define D_ 64
#define V_ELEMS (B_ * L_ * D_)   // 2,097,152 elements per [B,L,D] tensor
#define MFMA16 __builtin_amdgcn_mfma_f32_16x16x32_bf16

// ---- bf16 helpers (values are finite; no NaN handling needed) ----
__device__ __forceinline__ unsigned rne1(float f) {
    unsigned u = __builtin_bit_cast(unsigned, f);
    return (u + 0x7FFFu + ((u >> 16) & 1u)) >> 16;   // RNE f32->bf16 bits
}
__device__ __forceinline__ unsigned pack2(float a, float b) {
    return (rne1(a) & 0xFFFFu) | (rne1(b) << 16);
}
// v_cvt_pk_bf16_f32: a -> low16, b -> high16, RNE. Plain VALU op (no TRANS
// wait-state hazard) — guide-endorsed asm pattern.
__device__ __forceinline__ unsigned cvtpk(float a, float b) {
    unsigned r;
    asm("v_cvt_pk_bf16_f32 %0, %1, %2" : "=v"(r) : "v"(a), "v"(b));
    return r;
}

// Split f32 -> hi (truncated bf16, exact in fp32) + lo (RNE bf16 of residual).
__device__ __forceinline__ void split8(float4 a, float4 b, s16x8& hi, s16x8& lo) {
    float f[8] = {a.x, a.y, a.z, a.w, b.x, b.y, b.z, b.w};
    s16x8 h, l;
#pragma unroll
    for (int i = 0; i < 8; ++i) {
        unsigned u = __builtin_bit_cast(unsigned, f[i]);
        h[i] = (short)(u >> 16);
        float lf = f[i] - __builtin_bit_cast(float, u & 0xFFFF0000u);
        l[i] = (short)rne1(lf);
    }
    hi = h; lo = l;
}

// ---- fallback-only: v fp32 -> fp32 straight copy ----
__global__ void copy_v_kernel(const float4* __restrict__ v, float4* __restrict__ o) {
    int i = blockIdx.x * blockDim.x + threadIdx.x;
    o[i] = v[i];
}

// ---- prep: split q,k into hi/lo bf16 planes; also the v passthrough ----
__global__ void prep_qkv_kernel(const float4* __restrict__ q, const float4* __restrict__ k,
                                const float4* __restrict__ v,
                                uint2* __restrict__ qhi, uint2* __restrict__ qlo,
                                uint2* __restrict__ khi, uint2* __restrict__ klo,
                                float4* __restrict__ o) {
    int i = blockIdx.x * blockDim.x + threadIdx.x;   // grid covers V_ELEMS/4
    o[i] = v[i];
    float4 fq = q[i];
    float4 fk = k[i];
    unsigned u0 = __builtin_bit_cast(unsigned, fq.x), u1 = __builtin_bit_cast(unsigned, fq.y);
    unsigned u2 = __builtin_bit_cast(unsigned, fq.z), u3 = __builtin_bit_cast(unsigned, fq.w);
    qhi[i] = make_uint2((u0 >> 16) | (u1 & 0xFFFF0000u), (u2 >> 16) | (u3 & 0xFFFF0000u));
    qlo[i] = make_uint2(
        pack2(fq.x - __builtin_bit_cast(float, u0 & 0xFFFF0000u),
              fq.y - __builtin_bit_cast(float, u1 & 0xFFFF0000u)),
        pack2(fq.z - __builtin_bit_cast(float, u2 & 0xFFFF0000u),
              fq.w - __builtin_bit_cast(float, u3 & 0xFFFF0000u)));
    u0 = __builtin_bit_cast(unsigned, fk.x); u1 = __builtin_bit_cast(unsigned, fk.y);
    u2 = __builtin_bit_cast(unsigned, fk.z); u3 = __builtin_bit_cast(unsigned, fk.w);
    khi[i] = make_uint2((u0 >> 16) | (u1 & 0xFFFF0000u), (u2 >> 16) | (u3 & 0xFFFF0000u));
    klo[i] = make_uint2(
        pack2(fk.x - __builtin_bit_cast(float, u0 & 0xFFFF0000u),
              fk.y - __builtin_bit_cast(float, u1 & 0xFFFF0000u)),
        pack2(fk.z - __builtin_bit_cast(float, u2 & 0xFFFF0000u),
              fk.w - __builtin_bit_cast(float, u3 & 0xFFFF0000u)));
}

__device__ __forceinline__ void store4nt(float* p, unsigned u0, unsigned u1, float inv) {
    f32x4 w;
    w[0] = __builtin_bit_cast(float, u0 << 16) * inv;
    w[1] = __builtin_bit_cast(float, u0 & 0xFFFF0000u) * inv;
    w[2] = __builtin_bit_cast(float, u1 << 16) * inv;
    w[3] = __builtin_bit_cast(float, u1 & 0xFFFF0000u) * inv;
    __builtin_nontemporal_store(w, (f32x4*)p);
}

// ---- attention with LDS-transposed writeback (PRE path only) ----
// Block = (batch, 32 q-rows) as before; 16 waves x 128-wide k strips.
// Per 16-row q-tile: compute scores -> exp -> stash packed bf16 in LDS
// (XOR-swizzled), cross-wave row-sum reduce, then a FULLY-COALESCED
// writeback: 1024 threads stream contiguous float4s (1 KB/wave-instr,
// full 128B lines -> nt safe, no write amplification). Two tiles use
// double-buffered 64 KB stashes so tile-1 compute hides tile-0 store drain.
__global__ __launch_bounds__(1024, 4) void attn_lds_kernel(
    const ushort* __restrict__ qhi, const ushort* __restrict__ qlo,
    const ushort* __restrict__ khi, const ushort* __restrict__ klo,
    float* __restrict__ og) {
    // Bijective XCD swizzle: nwg = 1024, 8 XCDs -> XCD x gets logical blocks
    // [x*128, (x+1)*128) = exactly 2 batches -> K planes (1 MiB) L2-resident.
    const int bid  = ((blockIdx.x & 7) << 7) | (blockIdx.x >> 3);
    const int b    = bid >> 6;                 // 64 q-tiles (of 32 rows) per batch
    const int q0   = (bid & 63) << 5;          // first of 32 q rows
    const int tid  = threadIdx.x;
    const int wave = tid >> 6;                 // 0..15
    const int lane = tid & 63;
    const int nq   = lane & 15;
    const int quad = lane >> 4;

    // stash[buf][row16][dword]: row = q-row within tile, dword = k-col/2
    // (2 bf16 exps per dword). XOR-swizzle byte ^= (row<<3) kills the
    // 16-way write conflict (all-nq same bank) -> <=4-way; reads are
    // row-uniform per wave -> conflict-free.
    __shared__ unsigned stash[2][16][1024];    // 128 KiB
    __shared__ float wsum[16][16];
    __shared__ float inv_s[16];

    // B operand (q): two 16-row tiles, K(=d) split into halves of 32.
    s16x8 bhi[2][2], blo[2][2];
#pragma unroll
    for (int t = 0; t < 2; ++t) {
        const size_t off = ((size_t)(b * L_ + q0 + t * 16 + nq)) * D_ + quad * 8;
        bhi[t][0] = *(const s16x8*)(qhi + off);
        bhi[t][1] = *(const s16x8*)(qhi + off + 32);
        blo[t][0] = *(const s16x8*)(qlo + off);
        blo[t][1] = *(const s16x8*)(qlo + off + 32);
    }

    // This wave's 128-row k strip.
    const size_t kbase = ((size_t)(b * L_ + wave * 128 + nq)) * D_ + quad * 8;
    const size_t tstep = (size_t)16 * D_;

    const int w3 = wave >> 3;                  // writeback row parity
    const int c4 = tid & 511;                  // float4 index within a row

#pragma unroll
    for (int tt = 0; tt < 2; ++tt) {
        // ---- compute + stash for q-tile tt ----
        s16x8 ah0 = *(const s16x8*)(khi + kbase);
        s16x8 ah1 = *(const s16x8*)(khi + kbase + 32);
        s16x8 al0 = *(const s16x8*)(klo + kbase);
        s16x8 al1 = *(const s16x8*)(klo + kbase + 32);

        float s0 = 0.0f;
#pragma unroll
        for (int t = 0; t < 8; ++t) {
            const size_t noff = kbase + (size_t)((t + 1) & 7) * tstep;
            s16x8 nh0 = *(const s16x8*)(khi + noff);
            s16x8 nh1 = *(const s16x8*)(khi + noff + 32);
            s16x8 nl0 = *(const s16x8*)(klo + noff);
            s16x8 nl1 = *(const s16x8*)(klo + noff + 32);

            f32x4 c0 = {0.f, 0.f, 0.f, 0.f};
            c0 = MFMA16(ah0, bhi[tt][0], c0, 0, 0, 0);
            c0 = MFMA16(ah1, bhi[tt][1], c0, 0, 0, 0);
            c0 = MFMA16(ah0, blo[tt][0], c0, 0, 0, 0);
            c0 = MFMA16(ah1, blo[tt][1], c0, 0, 0, 0);
            c0 = MFMA16(al0, bhi[tt][0], c0, 0, 0, 0);
            c0 = MFMA16(al1, bhi[tt][1], c0, 0, 0, 0);

            // c0[reg] = score(q = q0+tt*16+nq, k = wave*128 + t*16 + quad*4 + reg)
            float e0 = __expf(c0[0]), e1 = __expf(c0[1]);
            float e2 = __expf(c0[2]), e3 = __expf(c0[3]);
            s0 += (e0 + e1) + (e2 + e3);
            // stash dwords at k-col/2 = wave*64 + t*8 + quad*2 (+0,1), row nq
            unsigned byteoff = ((unsigned)(wave * 64 + t * 8 + quad * 2) * 4u)
                               ^ ((unsigned)nq << 3);
            *(uint2*)((char*)&stash[tt][nq][0] + byteoff) =
                make_uint2(cvtpk(e0, e1), cvtpk(e2, e3));

            ah0 = nh0; ah1 = nh1; al0 = nl0; al1 = nl1;
        }

        // ---- row sums: quad-reduce, then cross-wave via LDS ----
        s0 += __shfl_xor(s0, 16); s0 += __shfl_xor(s0, 32);
        if (lane < 16) wsum[wave][nq] = s0;
        __syncthreads();                       // stash + wsum complete
        if (tid < 16) {
            float t0 = 0.f;
#pragma unroll
            for (int w = 0; w < 16; ++w) t0 += wsum[w][tid];
            inv_s[tid] = 1.0f / t0;
        }
        __syncthreads();                       // inv_s ready

        // ---- coalesced writeback: 8 passes x 2 rows x 8 KB ----
        float* obase = og + ((size_t)(b * L_ + q0 + tt * 16)) * L_;
#pragma unroll
        for (int p = 0; p < 8; ++p) {
            const int r = 2 * p + w3;
            unsigned byteoff = ((unsigned)c4 * 8u) ^ ((unsigned)r << 3);
            uint2 u = *(const uint2*)((const char*)&stash[tt][r][0] + byteoff);
            store4nt(obase + (size_t)r * L_ + (size_t)c4 * 4, u.x, u.y, inv_s[r]);
        }
        // no barrier: next tile uses the other stash buffer; wsum/inv_s
        // rewrites are gated by the next tile's own barriers.
    }
}

// ---- fallback (no workspace): R4's register-stash kernel, fp32 inputs ----
__global__ __launch_bounds__(1024, 4) void attn_fb_kernel(
    const float* __restrict__ qf, const float* __restrict__ kf,
    float* __restrict__ og) {
    const int bid  = ((blockIdx.x & 7) << 7) | (blockIdx.x >> 3);
    const int b    = bid >> 6;
    const int q0   = (bid & 63) << 5;
    const int tid  = threadIdx.x;
    const int wave = tid >> 6;
    const int lane = tid & 63;
    const int nq   = lane & 15;
    const int quad = lane >> 4;

    s16x8 bhi[2][2], blo[2][2];
#pragma unroll
    for (int t = 0; t < 2; ++t) {
        const size_t off = ((size_t)(b * L_ + q0 + t * 16 + nq)) * D_ + quad * 8;
        float4 a0 = *(const float4*)(qf + off), a1 = *(const float4*)(qf + off + 4);
        float4 a2 = *(const float4*)(qf + off + 32), a3 = *(const float4*)(qf + off + 36);
        split8(a0, a1, bhi[t][0], blo[t][0]);
        split8(a2, a3, bhi[t][1], blo[t][1]);
    }

    const size_t kbase = ((size_t)(b * L_ + wave * 128 + nq)) * D_ + quad * 8;
    const size_t tstep = (size_t)16 * D_;

    float s0 = 0.0f, s1 = 0.0f;
    unsigned pk0[16], pk1[16];

    s16x8 ah0, ah1, al0, al1;
    {
        float4 a0 = *(const float4*)(kf + kbase), a1 = *(const float4*)(kf + kbase + 4);
        float4 a2 = *(const float4*)(kf + kbase + 32), a3 = *(const float4*)(kf + kbase + 36);
        split8(a0, a1, ah0, al0);
        split8(a2, a3, ah1, al1);
    }

#pragma unroll
    for (int t = 0; t < 8; ++t) {
        const size_t noff = kbase + (size_t)((t + 1) & 7) * tstep;
        s16x8 nh0, nh1, nl0, nl1;
        {
            float4 a0 = *(const float4*)(kf + noff), a1 = *(const float4*)(kf + noff + 4);
            float4 a2 = *(const float4*)(kf + noff + 32), a3 = *(const float4*)(kf + noff + 36);
            split8(a0, a1, nh0, nl0);
            split8(a2, a3, nh1, nl1);
        }
        f32x4 c0 = {0.f, 0.f, 0.f, 0.f}, c1 = {0.f, 0.f, 0.f, 0.f};
        c0 = MFMA16(ah0, bhi[0][0], c0, 0, 0, 0);
        c1 = MFMA16(ah0, bhi[1][0], c1, 0, 0, 0);
        c0 = MFMA16(ah1, bhi[0][1], c0, 0, 0, 0);
        c1 = MFMA16(ah1, bhi[1][1], c1, 0, 0, 0);
        c0 = MFMA16(ah0, blo[0][0], c0, 0, 0, 0);
        c1 = MFMA16(ah0, blo[1][0], c1, 0, 0, 0);
        c0 = MFMA16(ah1, blo[0][1], c0, 0, 0, 0);
        c1 = MFMA16(ah1, blo[1][1], c1, 0, 0, 0);
        c0 = MFMA16(al0, bhi[0][0], c0, 0, 0, 0);
        c1 = MFMA16(al0, bhi[1][0], c1, 0, 0, 0);
        c0 = MFMA16(al1, bhi[0][1], c0, 0, 0, 0);
        c1 = MFMA16(al1, bhi[1][1], c1, 0, 0, 0);

        float e0 = __expf(c0[0]), e1 = __expf(c0[1]), e2 = __expf(c0[2]), e3 = __expf(c0[3]);
        s0 += (e0 + e1) + (e2 + e3);
        pk0[2 * t] = cvtpk(e0, e1); pk0[2 * t + 1] = cvtpk(e2, e3);
        float g0 = __expf(c1[0]), g1 = __expf(c1[1]), g2 = __expf(c1[2]), g3 = __expf(c1[3]);
        s1 += (g0 + g1) + (g2 + g3);
        pk1[2 * t] = cvtpk(g0, g1); pk1[2 * t + 1] = cvtpk(g2, g3);

        ah0 = nh0; ah1 = nh1; al0 = nl0; al1 = nl1;
    }

    s0 += __shfl_xor(s0, 16); s0 += __shfl_xor(s0, 32);
    s1 += __shfl_xor(s1, 16); s1 += __shfl_xor(s1, 32);
    __shared__ float wsum[16][2][16];
    if (lane < 16) { wsum[wave][0][lane] = s0; wsum[wave][1][lane] = s1; }
    __syncthreads();
    float t0 = 0.f, t1 = 0.f;
#pragma unroll
    for (int w = 0; w < 16; ++w) { t0 += wsum[w][0][nq]; t1 += wsum[w][1][nq]; }
    const float inv0 = 1.0f / t0;
    const float inv1 = 1.0f / t1;

    float* op0 = og + ((size_t)(b * L_ + q0 + nq)) * L_ + wave * 128 + quad * 4;
    float* op1 = op0 + (size_t)16 * L_;
#pragma unroll
    for (int t = 0; t < 8; ++t) {
        store4nt(op0 + t * 16, pk0[2 * t], pk0[2 * t + 1], inv0);
        store4nt(op1 + t * 16, pk1[2 * t], pk1[2 * t + 1], inv1);
    }
}

extern "C" void kernel_launch(void* const* d_in, const int* in_sizes, int n_in,
                              void* d_out, int out_size, void* d_ws, size_t ws_size,
                              hipStream_t stream) {
    const float* q = (const float*)d_in[0];
    const float* k = (const float*)d_in[1];
    const float* v = (const float*)d_in[2];
    float* out = (float*)d_out;

    // Output 1: attention [B, L, L] fp32 (256 MiB) after the v passthrough.
    float* att = out + (size_t)V_ELEMS;
    const size_t plane = (size_t)V_ELEMS;                  // elements per bf16 plane
    const size_t need  = 4 * plane * sizeof(ushort);       // qhi,qlo,khi,klo = 16 MiB
    ushort* qhi = (ushort*)d_ws;
    ushort* qlo = qhi + plane;
    ushort* khi = qlo + plane;
    ushort* klo = khi + plane;

    if (ws_size >= need) {
        prep_qkv_kernel<<<dim3(V_ELEMS / 4 / 256), dim3(256), 0, stream>>>(
            (const float4*)q, (const float4*)k, (const float4*)v,
            (uint2*)qhi, (uint2*)qlo, (uint2*)khi, (uint2*)klo, (float4*)out);
        attn_lds_kernel<<<dim3(B_ * (L_ / 32)), dim3(1024), 0, stream>>>(
            qhi, qlo, khi, klo, att);
    } else {
        copy_v_kernel<<<dim3(V_ELEMS / 4 / 256), dim3(256), 0, stream>>>(
            (const float4*)v, (float4*)out);
        attn_fb_kernel<<<dim3(B_ * (L_ / 32)), dim3(1024), 0, stream>>>(
            q, k, att);
    }
}

// Round 6
// 366.740 us; speedup vs baseline: 1.1031x; 1.1031x over previous
//
#include <hip/hip_runtime.h>
#include <hip/hip_bf16.h>

typedef short s16x8 __attribute__((ext_vector_type(8)));
typedef float f32x4 __attribute__((ext_vector_type(4)));

#define B_ 16
#define L_ 2048
#define D_ 64
#define V_ELEMS (B_ * L_ * D_)   // 2,097,152 elements per [B,L,D] tensor
#define MFMA16 __builtin_amdgcn_mfma_f32_16x16x32_bf16

// ---- bf16 helpers (values are finite; no NaN handling needed) ----
__device__ __forceinline__ unsigned rne1(float f) {
    unsigned u = __builtin_bit_cast(unsigned, f);
    return (u + 0x7FFFu + ((u >> 16) & 1u)) >> 16;   // RNE f32->bf16 bits
}
__device__ __forceinline__ unsigned pack2(float a, float b) {
    return (rne1(a) & 0xFFFFu) | (rne1(b) << 16);
}
// v_cvt_pk_bf16_f32: a -> low16, b -> high16, RNE. Plain VALU op (no TRANS
// wait-state hazard) — guide-endorsed asm pattern.
__device__ __forceinline__ unsigned cvtpk(float a, float b) {
    unsigned r;
    asm("v_cvt_pk_bf16_f32 %0, %1, %2" : "=v"(r) : "v"(a), "v"(b));
    return r;
}

// Split f32 -> hi (truncated bf16, exact in fp32) + lo (RNE bf16 of residual).
__device__ __forceinline__ void split8(float4 a, float4 b, s16x8& hi, s16x8& lo) {
    float f[8] = {a.x, a.y, a.z, a.w, b.x, b.y, b.z, b.w};
    s16x8 h, l;
#pragma unroll
    for (int i = 0; i < 8; ++i) {
        unsigned u = __builtin_bit_cast(unsigned, f[i]);
        h[i] = (short)(u >> 16);
        float lf = f[i] - __builtin_bit_cast(float, u & 0xFFFF0000u);
        l[i] = (short)rne1(lf);
    }
    hi = h; lo = l;
}

// ---- fallback-only: v fp32 -> fp32 straight copy ----
__global__ void copy_v_kernel(const float4* __restrict__ v, float4* __restrict__ o) {
    int i = blockIdx.x * blockDim.x + threadIdx.x;
    o[i] = v[i];
}

// ---- prep: split q,k into hi/lo bf16 planes; also the v passthrough ----
__global__ void prep_qkv_kernel(const float4* __restrict__ q, const float4* __restrict__ k,
                                const float4* __restrict__ v,
                                uint2* __restrict__ qhi, uint2* __restrict__ qlo,
                                uint2* __restrict__ khi, uint2* __restrict__ klo,
                                float4* __restrict__ o) {
    int i = blockIdx.x * blockDim.x + threadIdx.x;   // grid covers V_ELEMS/4
    o[i] = v[i];
    float4 fq = q[i];
    float4 fk = k[i];
    unsigned u0 = __builtin_bit_cast(unsigned, fq.x), u1 = __builtin_bit_cast(unsigned, fq.y);
    unsigned u2 = __builtin_bit_cast(unsigned, fq.z), u3 = __builtin_bit_cast(unsigned, fq.w);
    qhi[i] = make_uint2((u0 >> 16) | (u1 & 0xFFFF0000u), (u2 >> 16) | (u3 & 0xFFFF0000u));
    qlo[i] = make_uint2(
        pack2(fq.x - __builtin_bit_cast(float, u0 & 0xFFFF0000u),
              fq.y - __builtin_bit_cast(float, u1 & 0xFFFF0000u)),
        pack2(fq.z - __builtin_bit_cast(float, u2 & 0xFFFF0000u),
              fq.w - __builtin_bit_cast(float, u3 & 0xFFFF0000u)));
    u0 = __builtin_bit_cast(unsigned, fk.x); u1 = __builtin_bit_cast(unsigned, fk.y);
    u2 = __builtin_bit_cast(unsigned, fk.z); u3 = __builtin_bit_cast(unsigned, fk.w);
    khi[i] = make_uint2((u0 >> 16) | (u1 & 0xFFFF0000u), (u2 >> 16) | (u3 & 0xFFFF0000u));
    klo[i] = make_uint2(
        pack2(fk.x - __builtin_bit_cast(float, u0 & 0xFFFF0000u),
              fk.y - __builtin_bit_cast(float, u1 & 0xFFFF0000u)),
        pack2(fk.z - __builtin_bit_cast(float, u2 & 0xFFFF0000u),
              fk.w - __builtin_bit_cast(float, u3 & 0xFFFF0000u)));
}

// PLAIN cached store (the single A/B variable vs R4's nontemporal version):
// goes through L2 write-back, so adjacent 64 B segments merge into full
// dirty lines that evict in bulk — the same path the 6.3 TB/s fill uses.
__device__ __forceinline__ void store4(float* p, unsigned u0, unsigned u1, float inv) {
    f32x4 w;
    w[0] = __builtin_bit_cast(float, u0 << 16) * inv;
    w[1] = __builtin_bit_cast(float, u0 & 0xFFFF0000u) * inv;
    w[2] = __builtin_bit_cast(float, u1 << 16) * inv;
    w[3] = __builtin_bit_cast(float, u1 & 0xFFFF0000u) * inv;
    *(f32x4*)p = w;
}

// ---- attention: block = (batch, 32 q-rows); 16 waves x 128-wide k strips.
// SINGLE pass over k (stash exps as packed bf16); stash is 32 VGPRs/wave so
// the kernel fits the 128-VGPR cap of 4 waves/SIMD -> 16 waves/CU.
// Identical to R4 except: plain stores instead of nontemporal.
template <bool PRE>
__global__ __launch_bounds__(1024, 4) void attn_kernel(
    const float* __restrict__ qf, const float* __restrict__ kf,
    const ushort* __restrict__ qhi, const ushort* __restrict__ qlo,
    const ushort* __restrict__ khi, const ushort* __restrict__ klo,
    float* __restrict__ og) {
    // Bijective XCD swizzle: nwg = 1024, 8 XCDs -> XCD x gets logical blocks
    // [x*128, (x+1)*128) = exactly 2 batches -> K planes (1 MiB) L2-resident.
    const int bid  = ((blockIdx.x & 7) << 7) | (blockIdx.x >> 3);
    const int b    = bid >> 6;                 // 64 q-tiles (of 32 rows) per batch
    const int q0   = (bid & 63) << 5;          // first of 32 q rows
    const int tid  = threadIdx.x;
    const int wave = tid >> 6;                 // 0..15
    const int lane = tid & 63;
    const int nq   = lane & 15;
    const int quad = lane >> 4;

    // B operand (q): two 16-row tiles, K(=d) split into halves of 32.
    s16x8 bhi[2][2], blo[2][2];
#pragma unroll
    for (int t = 0; t < 2; ++t) {
        const size_t off = ((size_t)(b * L_ + q0 + t * 16 + nq)) * D_ + quad * 8;
        if constexpr (PRE) {
            bhi[t][0] = *(const s16x8*)(qhi + off);
            bhi[t][1] = *(const s16x8*)(qhi + off + 32);
            blo[t][0] = *(const s16x8*)(qlo + off);
            blo[t][1] = *(const s16x8*)(qlo + off + 32);
        } else {
            float4 a0 = *(const float4*)(qf + off), a1 = *(const float4*)(qf + off + 4);
            float4 a2 = *(const float4*)(qf + off + 32), a3 = *(const float4*)(qf + off + 36);
            split8(a0, a1, bhi[t][0], blo[t][0]);
            split8(a2, a3, bhi[t][1], blo[t][1]);
        }
    }

    // This wave's 128-row k strip.
    const size_t kbase = ((size_t)(b * L_ + wave * 128 + nq)) * D_ + quad * 8;
    const size_t tstep = (size_t)16 * D_;

    float s0 = 0.0f, s1 = 0.0f;
    unsigned pk0[16], pk1[16];   // 8 subtiles x 4 exps packed into 2 dwords, per q-tile

    // Prefetch subtile 0.
    s16x8 ah0, ah1, al0, al1;
    if constexpr (PRE) {
        ah0 = *(const s16x8*)(khi + kbase);
        ah1 = *(const s16x8*)(khi + kbase + 32);
        al0 = *(const s16x8*)(klo + kbase);
        al1 = *(const s16x8*)(klo + kbase + 32);
    } else {
        float4 a0 = *(const float4*)(kf + kbase), a1 = *(const float4*)(kf + kbase + 4);
        float4 a2 = *(const float4*)(kf + kbase + 32), a3 = *(const float4*)(kf + kbase + 36);
        split8(a0, a1, ah0, al0);
        split8(a2, a3, ah1, al1);
    }

#pragma unroll
    for (int t = 0; t < 8; ++t) {
        // Prefetch subtile t+1 (t=7 redundantly reloads t=0; L1-hot, harmless).
        const size_t noff = kbase + (size_t)((t + 1) & 7) * tstep;
        s16x8 nh0, nh1, nl0, nl1;
        if constexpr (PRE) {
            nh0 = *(const s16x8*)(khi + noff);
            nh1 = *(const s16x8*)(khi + noff + 32);
            nl0 = *(const s16x8*)(klo + noff);
            nl1 = *(const s16x8*)(klo + noff + 32);
        } else {
            float4 a0 = *(const float4*)(kf + noff), a1 = *(const float4*)(kf + noff + 4);
            float4 a2 = *(const float4*)(kf + noff + 32), a3 = *(const float4*)(kf + noff + 36);
            split8(a0, a1, nh0, nl0);
            split8(a2, a3, nh1, nl1);
        }

        f32x4 c0 = {0.f, 0.f, 0.f, 0.f}, c1 = {0.f, 0.f, 0.f, 0.f};
        c0 = MFMA16(ah0, bhi[0][0], c0, 0, 0, 0);
        c1 = MFMA16(ah0, bhi[1][0], c1, 0, 0, 0);
        c0 = MFMA16(ah1, bhi[0][1], c0, 0, 0, 0);
        c1 = MFMA16(ah1, bhi[1][1], c1, 0, 0, 0);
        c0 = MFMA16(ah0, blo[0][0], c0, 0, 0, 0);
        c1 = MFMA16(ah0, blo[1][0], c1, 0, 0, 0);
        c0 = MFMA16(ah1, blo[0][1], c0, 0, 0, 0);
        c1 = MFMA16(ah1, blo[1][1], c1, 0, 0, 0);
        c0 = MFMA16(al0, bhi[0][0], c0, 0, 0, 0);
        c1 = MFMA16(al0, bhi[1][0], c1, 0, 0, 0);
        c0 = MFMA16(al1, bhi[0][1], c0, 0, 0, 0);
        c1 = MFMA16(al1, bhi[1][1], c1, 0, 0, 0);

        // c[reg] = score(q = q0+tile*16+nq, k = wave*128 + t*16 + quad*4 + reg)
        float e0 = __expf(c0[0]), e1 = __expf(c0[1]), e2 = __expf(c0[2]), e3 = __expf(c0[3]);
        s0 += (e0 + e1) + (e2 + e3);
        pk0[2 * t]     = cvtpk(e0, e1);
        pk0[2 * t + 1] = cvtpk(e2, e3);
        float g0 = __expf(c1[0]), g1 = __expf(c1[1]), g2 = __expf(c1[2]), g3 = __expf(c1[3]);
        s1 += (g0 + g1) + (g2 + g3);
        pk1[2 * t]     = cvtpk(g0, g1);
        pk1[2 * t + 1] = cvtpk(g2, g3);

        ah0 = nh0; ah1 = nh1; al0 = nl0; al1 = nl1;
    }

    // Row sums: reduce across quads, then across the 16 waves via LDS.
    s0 += __shfl_xor(s0, 16); s0 += __shfl_xor(s0, 32);
    s1 += __shfl_xor(s1, 16); s1 += __shfl_xor(s1, 32);
    __shared__ float wsum[16][2][16];
    if (lane < 16) { wsum[wave][0][lane] = s0; wsum[wave][1][lane] = s1; }
    __syncthreads();
    float t0 = 0.f, t1 = 0.f;
#pragma unroll
    for (int w = 0; w < 16; ++w) { t0 += wsum[w][0][nq]; t1 += wsum[w][1][nq]; }
    const float inv0 = 1.0f / t0;
    const float inv1 = 1.0f / t1;

    // Writeback: normalized probs, fp32, PLAIN cached stores (A/B vs R4's nt).
    float* op0 = og + ((size_t)(b * L_ + q0 + nq)) * L_ + wave * 128 + quad * 4;
    float* op1 = op0 + (size_t)16 * L_;
#pragma unroll
    for (int t = 0; t < 8; ++t) {
        store4(op0 + t * 16, pk0[2 * t], pk0[2 * t + 1], inv0);
        store4(op1 + t * 16, pk1[2 * t], pk1[2 * t + 1], inv1);
    }
}

extern "C" void kernel_launch(void* const* d_in, const int* in_sizes, int n_in,
                              void* d_out, int out_size, void* d_ws, size_t ws_size,
                              hipStream_t stream) {
    const float* q = (const float*)d_in[0];
    const float* k = (const float*)d_in[1];
    const float* v = (const float*)d_in[2];
    float* out = (float*)d_out;

    // Output 1: attention [B, L, L] fp32 (256 MiB) after the v passthrough.
    float* att = out + (size_t)V_ELEMS;
    const size_t plane = (size_t)V_ELEMS;                  // elements per bf16 plane
    const size_t need  = 4 * plane * sizeof(ushort);       // qhi,qlo,khi,klo = 16 MiB
    ushort* qhi = (ushort*)d_ws;
    ushort* qlo = qhi + plane;
    ushort* khi = qlo + plane;
    ushort* klo = khi + plane;

    if (ws_size >= need) {
        prep_qkv_kernel<<<dim3(V_ELEMS / 4 / 256), dim3(256), 0, stream>>>(
            (const float4*)q, (const float4*)k, (const float4*)v,
            (uint2*)qhi, (uint2*)qlo, (uint2*)khi, (uint2*)klo, (float4*)out);
        attn_kernel<true><<<dim3(B_ * (L_ / 32)), dim3(1024), 0, stream>>>(
            q, k, qhi, qlo, khi, klo, att);
    } else {
        copy_v_kernel<<<dim3(V_ELEMS / 4 / 256), dim3(256), 0, stream>>>(
            (const float4*)v, (float4*)out);
        attn_kernel<false><<<dim3(B_ * (L_ / 32)), dim3(1024), 0, stream>>>(
            q, k, qhi, qlo, khi, klo, att);
    }
}